// Round 8
// baseline (641.322 us; speedup 1.0000x reference)
//
#include <hip/hip_runtime.h>
#include <hip/hip_bf16.h>

typedef unsigned char u8;
typedef float f32x4 __attribute__((ext_vector_type(4)));
typedef int int4v __attribute__((ext_vector_type(4)));
typedef int int8v __attribute__((ext_vector_type(8)));

#define B_ROWS 8192
#define D_DIM  1024
#define FP8_SCALE 16.0f          // store x*16 in e4m3; acc = 256 * s_true
#define ACC_UNSCALE (1.0f/256.0f)
#define NBLK 512                 // 2 blocks/CU needed; capacity >=4 -> deadlock-proof

// ---------------------------------------------------------------------------
// Workspace layout (bytes):
//   [0,      32768)   ppq[8192]
//   [32768,  65536)   ppp[8192]
//   [65536,  98304)   ppd[8192]
//   [98304,  98816)   bpart[32] float4
//   [98816,  98880)   ctrs[3]  (zeroed by 64B memset each launch)
//   [131072, +4MiB)   gpart[128][8192]
//   [+4MiB,  +8MiB)   qn fp8
//   [...  ,  +8MiB)   pn fp8
// ---------------------------------------------------------------------------

__device__ __forceinline__ void grid_barrier(int* ctr) {
    __syncthreads();
    if (threadIdx.x == 0) {
        __threadfence();   // release: drain this block's writes device-wide
        __hip_atomic_fetch_add(ctr, 1, __ATOMIC_ACQ_REL, __HIP_MEMORY_SCOPE_AGENT);
        while (__hip_atomic_load(ctr, __ATOMIC_ACQUIRE, __HIP_MEMORY_SCOPE_AGENT) < NBLK)
            __builtin_amdgcn_s_sleep(2);
        __threadfence();   // acquire: invalidate stale cached lines
    }
    __syncthreads();
}

__global__ void __launch_bounds__(256, 4) mega_kernel(
    const float* __restrict__ sq, const float* __restrict__ sp,
    const float* __restrict__ tq, const float* __restrict__ tp,
    int* __restrict__ qn, int* __restrict__ pn,
    float* __restrict__ ppq, float* __restrict__ ppp, float* __restrict__ ppd,
    float* __restrict__ gpart, float4* __restrict__ bpart,
    int* __restrict__ ctrs, float* __restrict__ out)
{
    __shared__ u8 smA[128 * 128];   // 16 KiB
    __shared__ u8 smB[128 * 128];   // 16 KiB
    __shared__ float red[4][4];

    const int tid  = threadIdx.x;
    const int wave = tid >> 6;
    const int lane = tid & 63;
    const int b    = blockIdx.x;

    // ======================= phase 1: prep (4 rows/wave) ====================
    #pragma unroll 1
    for (int i = 0; i < 4; ++i) {
        const int r = b * 4 + wave + i * 2048;
        const size_t rb4 = (size_t)r * (D_DIM / 4);
        const float4* Q4 = (const float4*)sq + rb4;
        const float4* P4 = (const float4*)sp + rb4;
        const float4* A4 = (const float4*)tq + rb4;
        const float4* B4 = (const float4*)tp + rb4;

        float4 qv[4], pv[4];
        float sq2 = 0.f, sp2 = 0.f, dq = 0.f, dp = 0.f, qp = 0.f;
        #pragma unroll
        for (int j = 0; j < 4; ++j) {
            const int idx = j * 64 + lane;
            float4 q = Q4[idx], p = P4[idx], a = A4[idx], bb = B4[idx];
            qv[j] = q; pv[j] = p;
            sq2 += q.x*q.x + q.y*q.y + q.z*q.z + q.w*q.w;
            sp2 += p.x*p.x + p.y*p.y + p.z*p.z + p.w*p.w;
            float dx = q.x-a.x, dy = q.y-a.y, dz = q.z-a.z, dw = q.w-a.w;
            dq += dx*dx + dy*dy + dz*dz + dw*dw;
            dx = p.x-bb.x; dy = p.y-bb.y; dz = p.z-bb.z; dw = p.w-bb.w;
            dp += dx*dx + dy*dy + dz*dz + dw*dw;
            qp += q.x*p.x + q.y*p.y + q.z*p.z + q.w*p.w;
        }
        #pragma unroll
        for (int m = 1; m <= 32; m <<= 1) {
            sq2 += __shfl_xor(sq2, m);
            sp2 += __shfl_xor(sp2, m);
            dq  += __shfl_xor(dq, m);
            dp  += __shfl_xor(dp, m);
            qp  += __shfl_xor(qp, m);
        }
        const float rq = 1.0f / fmaxf(sqrtf(sq2), 1e-8f);
        const float rp = 1.0f / fmaxf(sqrtf(sp2), 1e-8f);
        if (lane == 0) {
            ppq[r] = dq;
            ppp[r] = dp;
            ppd[r] = qp * rq * rp;   // exact fp32 diagonal cosine
        }
        const float fq = rq * FP8_SCALE;
        const float fp = rp * FP8_SCALE;
        int* qrow = qn + (size_t)r * (D_DIM / 4);
        int* prow = pn + (size_t)r * (D_DIM / 4);
        #pragma unroll
        for (int j = 0; j < 4; ++j) {
            const int idx = j * 64 + lane;
            int pk = __builtin_amdgcn_cvt_pk_fp8_f32(qv[j].x * fq, qv[j].y * fq, 0, false);
            pk     = __builtin_amdgcn_cvt_pk_fp8_f32(qv[j].z * fq, qv[j].w * fq, pk, true);
            qrow[idx] = pk;
            pk = __builtin_amdgcn_cvt_pk_fp8_f32(pv[j].x * fp, pv[j].y * fp, 0, false);
            pk = __builtin_amdgcn_cvt_pk_fp8_f32(pv[j].z * fp, pv[j].w * fp, pk, true);
            prow[idx] = pk;
        }
    }
    grid_barrier(&ctrs[0]);

    // ======================= phase 2: gemm (8 tiles/block) ==================
    // R4-exact inner structure: 128x128 tile, 4 waves 2x2, BK=128,
    // XOR-16B-chunk LDS swizzle, grouped lo/hi ds_read_b128, MX fp8 MFMA.
    {
        const int lrow   = lane >> 3;
        const int gchunk = (lane & 7) ^ lrow;
        const int quad   = lane >> 4;
        const int rw     = lane & 15;
        const int r7     = lane & 7;
        const int arow0  = (wave >> 1) * 64;
        const int bcol0  = (wave & 1) * 64;
        const int off_lo = ((2 * quad) ^ r7) * 16;
        const int off_hi = ((2 * quad + 1) ^ r7) * 16;

        union Frag { int8v v8; struct { int4v lo, hi; } h; };

        #pragma unroll 1
        for (int ti = 0; ti < 8; ++ti) {
            const int t  = b + ti * NBLK;       // 0..4095
            const int bn = t & 63;              // fast index: A-tile L2 reuse
            const int bm = t >> 6;
            const u8* Ag = (const u8*)qn + ((size_t)bm * 128) * D_DIM + gchunk * 16;
            const u8* Bg = (const u8*)pn + ((size_t)bn * 128) * D_DIM + gchunk * 16;

            f32x4 acc[4][4];
            #pragma unroll
            for (int i = 0; i < 4; ++i)
                #pragma unroll
                for (int j = 0; j < 4; ++j)
                    acc[i][j] = (f32x4){0.f, 0.f, 0.f, 0.f};

            for (int k0 = 0; k0 < D_DIM; k0 += 128) {
                #pragma unroll
                for (int i = 0; i < 4; ++i) {
                    const int r0 = wave * 32 + i * 8;
                    __builtin_amdgcn_global_load_lds(
                        (const __attribute__((address_space(1))) void*)(Ag + (size_t)(r0 + lrow) * D_DIM + k0),
                        (__attribute__((address_space(3))) void*)(smA + r0 * 128), 16, 0, 0);
                    __builtin_amdgcn_global_load_lds(
                        (const __attribute__((address_space(1))) void*)(Bg + (size_t)(r0 + lrow) * D_DIM + k0),
                        (__attribute__((address_space(3))) void*)(smB + r0 * 128), 16, 0, 0);
                }
                __syncthreads();

                Frag af[4], bf[4];
                #pragma unroll
                for (int mi = 0; mi < 4; ++mi)
                    af[mi].h.lo = *(const int4v*)(smA + (arow0 + mi * 16 + rw) * 128 + off_lo);
                #pragma unroll
                for (int ni = 0; ni < 4; ++ni)
                    bf[ni].h.lo = *(const int4v*)(smB + (bcol0 + ni * 16 + rw) * 128 + off_lo);
                __builtin_amdgcn_sched_barrier(0);
                #pragma unroll
                for (int mi = 0; mi < 4; ++mi)
                    af[mi].h.hi = *(const int4v*)(smA + (arow0 + mi * 16 + rw) * 128 + off_hi);
                #pragma unroll
                for (int ni = 0; ni < 4; ++ni)
                    bf[ni].h.hi = *(const int4v*)(smB + (bcol0 + ni * 16 + rw) * 128 + off_hi);

                #pragma unroll
                for (int mi = 0; mi < 4; ++mi)
                    #pragma unroll
                    for (int ni = 0; ni < 4; ++ni)
                        acc[mi][ni] = __builtin_amdgcn_mfma_scale_f32_16x16x128_f8f6f4(
                            af[mi].v8, bf[ni].v8, acc[mi][ni],
                            0, 0,                 // cbsz=fp8, blgp=fp8
                            0, 0x7f7f7f7f,        // scale A = 1.0
                            0, 0x7f7f7f7f);       // scale B = 1.0
                __syncthreads();
            }

            // epilogue: per-row exp-sum over this wave's 64 columns
            float esum[4][4];
            #pragma unroll
            for (int mi = 0; mi < 4; ++mi)
                #pragma unroll
                for (int r = 0; r < 4; ++r) {
                    float s = 0.f;
                    #pragma unroll
                    for (int ni = 0; ni < 4; ++ni)
                        s += __expf(acc[mi][ni][r] * ACC_UNSCALE);
                    esum[mi][r] = s;
                }
            #pragma unroll
            for (int m = 1; m <= 8; m <<= 1)
                #pragma unroll
                for (int mi = 0; mi < 4; ++mi)
                    #pragma unroll
                    for (int r = 0; r < 4; ++r)
                        esum[mi][r] += __shfl_xor(esum[mi][r], m);

            if (rw == 0) {
                float* dst = gpart + ((size_t)(bn * 2 + (wave & 1))) * B_ROWS
                           + bm * 128 + arow0;
                #pragma unroll
                for (int mi = 0; mi < 4; ++mi)
                    #pragma unroll
                    for (int r = 0; r < 4; ++r)
                        dst[mi * 16 + quad * 4 + r] = esum[mi][r];
            }
        }
    }
    grid_barrier(&ctrs[1]);

    // ======================= phase 3: reduce (32 blocks) ====================
    if (b < 32) {
        const int r = b * 256 + tid;
        float s = 0.f;
        #pragma unroll 8
        for (int j = 0; j < 128; ++j) s += gpart[(size_t)j * B_ROWS + r];
        float ls = logf(s);
        float v2 = ppq[r], v3 = ppp[r], v4 = ppd[r];
        #pragma unroll
        for (int m = 1; m <= 32; m <<= 1) {
            ls += __shfl_xor(ls, m);
            v2 += __shfl_xor(v2, m);
            v3 += __shfl_xor(v3, m);
            v4 += __shfl_xor(v4, m);
        }
        if (lane == 0) {
            red[wave][0] = ls; red[wave][1] = v2;
            red[wave][2] = v3; red[wave][3] = v4;
        }
        __syncthreads();
        if (tid == 0) {
            float4 o;
            o.x = red[0][0] + red[1][0] + red[2][0] + red[3][0];
            o.y = red[0][1] + red[1][1] + red[2][1] + red[3][1];
            o.z = red[0][2] + red[1][2] + red[2][2] + red[3][2];
            o.w = red[0][3] + red[1][3] + red[2][3] + red[3][3];
            bpart[b] = o;
        }
    }
    grid_barrier(&ctrs[2]);

    // ======================= phase 4: finalize (block 0) ====================
    if (b == 0 && tid < 32) {
        float4 v = bpart[tid];
        #pragma unroll
        for (int m = 1; m <= 16; m <<= 1) {
            v.x += __shfl_xor(v.x, m);
            v.y += __shfl_xor(v.y, m);
            v.z += __shfl_xor(v.z, m);
            v.w += __shfl_xor(v.w, m);
        }
        if (tid == 0) {
            const float inv_bd = 1.0f / ((float)B_ROWS * (float)D_DIM);
            float distill   = 0.5f * (v.y + v.z) * inv_bd;
            float retrieval = (v.x - v.w) / (float)B_ROWS;
            out[0] = 0.5f * distill + 0.5f * retrieval;
        }
    }
}

extern "C" void kernel_launch(void* const* d_in, const int* in_sizes, int n_in,
                              void* d_out, int out_size, void* d_ws, size_t ws_size,
                              hipStream_t stream) {
    const float* sq = (const float*)d_in[0];
    const float* sp = (const float*)d_in[1];
    const float* tq = (const float*)d_in[2];
    const float* tp = (const float*)d_in[3];

    char* ws = (char*)d_ws;
    float*  ppq   = (float*)(ws);
    float*  ppp   = (float*)(ws + 32768);
    float*  ppd   = (float*)(ws + 65536);
    float4* bpart = (float4*)(ws + 98304);
    int*    ctrs  = (int*)(ws + 98816);
    float*  gpart = (float*)(ws + 131072);                        // 4 MiB
    int*    qn    = (int*)(ws + 131072 + (size_t)128 * B_ROWS * 4);
    int*    pn    = (int*)((char*)qn + (size_t)B_ROWS * D_DIM);

    hipMemsetAsync(ctrs, 0, 64, stream);
    mega_kernel<<<NBLK, 256, 0, stream>>>(sq, sp, tq, tp, qn, pn,
                                          ppq, ppp, ppd, gpart, bpart,
                                          ctrs, (float*)d_out);
}